// Round 12
// baseline (146.559 us; speedup 1.0000x reference)
//
#include <hip/hip_runtime.h>

#define KEHALF 7.199822675975274f
#define CUTOFF 12.0f

typedef float    fx4 __attribute__((ext_vector_type(4)));
typedef float    fx2 __attribute__((ext_vector_type(2)));
typedef int      ix4 __attribute__((ext_vector_type(4)));
typedef int      ix2 __attribute__((ext_vector_type(2)));
typedef _Float16 hx4 __attribute__((ext_vector_type(4)));

static __device__ __forceinline__ hx4 as_h4(ix2 v) { union { ix2 i; hx4 h; } u; u.i = v; return u.h; }
static __device__ __forceinline__ float h2f_bits(unsigned int hb) {
    union { unsigned short u; _Float16 h; } c; c.u = (unsigned short)hb; return (float)c.h;
}
static __device__ __forceinline__ unsigned int f2h_bits(float f) {
    union { _Float16 h; unsigned short u; } c; c.h = (_Float16)f; return (unsigned int)c.u;
}

// ---- Pack kernel: T[atom] = 16 B: d0,d1 = {q,mu} fp16; d2,d3 = 5 quad vals
// (traceless-symmetric reduced) at 13/12-bit rounded fp16. Table 1.6 MB ->
// fully L2-resident per XCD. Gathers from T must use NORMAL caching —
// nt-hinted gathers defeat L2 retention (round-10: FETCH 44->134 MB, 2x time).
__global__ __launch_bounds__(256)
void pack_atoms16(const float* __restrict__ q,
                  const float* __restrict__ mu,
                  const float* __restrict__ quad,
                  unsigned int* __restrict__ T, int N) {
    int a = blockIdx.x * blockDim.x + threadIdx.x;
    if (a >= N) return;
    const float* m = mu + 3 * a;
    const float* Q = quad + 9 * a;
    float Q00 = Q[0], Q01 = Q[1], Q02 = Q[2];
    float Q10 = Q[3], Q11 = Q[4], Q12 = Q[5];
    float Q20 = Q[6], Q21 = Q[7], Q22 = Q[8];
    float tr3 = (Q00 + Q11 + Q22) * (1.0f / 3.0f);
    unsigned int t00 = ((f2h_bits(Q00 - tr3) + 4u) >> 3) & 0x1FFFu;
    unsigned int t11 = ((f2h_bits(Q11 - tr3) + 4u) >> 3) & 0x1FFFu;
    unsigned int t01 = ((f2h_bits(Q01 + Q10) + 4u) >> 3) & 0x1FFFu;
    unsigned int t02 = ((f2h_bits(Q02 + Q20) + 4u) >> 3) & 0x1FFFu;
    unsigned int t12 = ((f2h_bits(Q12 + Q21) + 8u) >> 4) & 0xFFFu;  // 12-bit
    unsigned int d0 = f2h_bits(q[a]) | (f2h_bits(m[0]) << 16);
    unsigned int d1 = f2h_bits(m[1]) | (f2h_bits(m[2]) << 16);
    unsigned int d2 = t00 | (t11 << 13) | ((t12 & 0x3Fu) << 26);
    unsigned int d3 = t01 | (t02 << 13) | ((t12 >> 6) << 26);
    ix4 e = {(int)d0, (int)d1, (int)d2, (int)d3};
    *reinterpret_cast<ix4*>(T + 4 * (long)a) = e;
}

// ---- Per-edge physics (decodes packed v-entry) ----
static __device__ __forceinline__ float edgeE(float d, float vx, float vy, float vz,
                                              hx4 au, ix4 gv) {
    float inv_d = __builtin_amdgcn_rcpf(d);
    float x = fminf(fmaxf(d * 0.5f, 0.0f), 1.0f);
    float x2 = x * x, x3 = x2 * x;
    float sw = 1.0f - x3 * (10.0f - 15.0f * x + 6.0f * x2);
    float chi = sw * __builtin_amdgcn_rsqf(d * d + 1.0f) + (1.0f - sw) * inv_d;
    float chi2 = chi * chi, chi3 = chi2 * chi;

    float qu    = (float)au[0];
    float mux_u = (float)au[1], muy_u = (float)au[2], muz_u = (float)au[3];

    ix2 vlo = {gv.x, gv.y};
    hx4 av = as_h4(vlo);
    float qv    = (float)av[0];
    float mux_v = (float)av[1], muy_v = (float)av[2], muz_v = (float)av[3];

    unsigned int d2b = (unsigned int)gv.z, d3b = (unsigned int)gv.w;
    float p00 = h2f_bits((d2b & 0x1FFFu) << 3);
    float p11 = h2f_bits(((d2b >> 13) & 0x1FFFu) << 3);
    float s01 = h2f_bits((d3b & 0x1FFFu) << 3);
    float s02 = h2f_bits(((d3b >> 13) & 0x1FFFu) << 3);
    float s12 = h2f_bits((((d3b >> 26) << 6) | (d2b >> 26)) << 4);
    float p22 = -(p00 + p11);  // traceless: exact reconstruction

    float dot_uv = (vx * mux_v + vy * muy_v + vz * muz_v) * inv_d;
    float dot_vu = (vx * mux_u + vy * muy_u + vz * muz_u) * inv_d;
    float mudot  = mux_u * mux_v + muy_u * muy_v + muz_u * muz_v;

    float E = qu * qv * chi
            + 2.0f * qu * dot_uv * chi2
            + (mudot - 3.0f * dot_uv * dot_vu) * chi3;

    float s = vx * (vx * p00 + vy * s01 + vz * s02)
            + vy * (vy * p11 + vz * s12)
            + vz * (vz * p22);
    E += qu * (s * inv_d * inv_d) * chi3;
    return (d <= CUTOFF) ? (KEHALF * E) : 0.0f;
}

// ---- Main kernel: 2 edges/thread -> 2x grid, max wave concurrency ----
__global__ __launch_bounds__(256)
void damped_elec_p16e2(const float* __restrict__ dist,
                       const float* __restrict__ vec,
                       const unsigned int* __restrict__ T,
                       const int* __restrict__ iu,
                       const int* __restrict__ iv,
                       float* __restrict__ out, int E) {
    int t = blockIdx.x * blockDim.x + threadIdx.x;
    int e0 = t * 2;
    if (e0 >= E) return;

    if (e0 + 2 <= E) {
        // Index loads first (head of critical chain) — normal caching.
        ix2 u2 = *reinterpret_cast<const ix2*>(iu + e0);
        ix2 v2 = *reinterpret_cast<const ix2*>(iv + e0);
        // Streaming data: non-temporal (keep L2 for the atom table).
        fx2 d2v = __builtin_nontemporal_load(reinterpret_cast<const fx2*>(dist + e0));
        fx2 w0 = __builtin_nontemporal_load(reinterpret_cast<const fx2*>(vec + 3 * e0));
        fx2 w1 = __builtin_nontemporal_load(reinterpret_cast<const fx2*>(vec + 3 * e0 + 2));
        fx2 w2 = __builtin_nontemporal_load(reinterpret_cast<const fx2*>(vec + 3 * e0 + 4));

        int ub[2]  = {u2.x, u2.y};
        int vbi[2] = {v2.x, v2.y};

        // Gather phase: 2 loads per edge, NORMAL caching (L2-resident table).
        ix2 gu[2];
        ix4 gv[2];
#pragma unroll
        for (int k = 0; k < 2; ++k) {
            const unsigned int* pu = T + ((long)ub[k] << 2);
            const unsigned int* pv = T + ((long)vbi[k] << 2);
            gu[k] = *reinterpret_cast<const ix2*>(pu);
            gv[k] = *reinterpret_cast<const ix4*>(pv);
        }

        // Keep-live fence: one latency window, no sinking into compute.
        asm volatile("" : "+v"(d2v), "+v"(w0), "+v"(w1), "+v"(w2),
                          "+v"(gu[0]), "+v"(gu[1]),
                          "+v"(gv[0]), "+v"(gv[1]) :: "memory");

        float db[2]  = {d2v.x, d2v.y};
        float vvv[6] = {w0.x, w0.y, w1.x, w1.y, w2.x, w2.y};

        float res[2];
#pragma unroll
        for (int k = 0; k < 2; ++k) {
            res[k] = edgeE(db[k], vvv[3 * k + 0], vvv[3 * k + 1], vvv[3 * k + 2],
                           as_h4(gu[k]), gv[k]);
        }
        fx2 o2 = {res[0], res[1]};
        __builtin_nontemporal_store(o2, reinterpret_cast<fx2*>(out + e0));
    } else {
        // Scalar tail (E % 2 != 0 only).
        for (int e = e0; e < E; ++e) {
            int u = iu[e], v = iv[e];
            ix2 gu = *reinterpret_cast<const ix2*>(T + ((long)u << 2));
            ix4 gv = *reinterpret_cast<const ix4*>(T + ((long)v << 2));
            out[e] = edgeE(dist[e], vec[3 * e + 0], vec[3 * e + 1], vec[3 * e + 2],
                           as_h4(gu), gv);
        }
    }
}

// ---- Fallback (ws too small): direct scalar-gather kernel ----
__global__ __launch_bounds__(256)
void damped_elec_direct(const float* __restrict__ dist,
                        const float* __restrict__ vec,
                        const float* __restrict__ q,
                        const float* __restrict__ mu,
                        const float* __restrict__ quad,
                        const int* __restrict__ idx_u,
                        const int* __restrict__ idx_v,
                        float* __restrict__ out, int E) {
    int e = blockIdx.x * blockDim.x + threadIdx.x;
    if (e >= E) return;
    float d = dist[e];
    int u = idx_u[e], v = idx_v[e];
    float vx = vec[3 * e + 0], vy = vec[3 * e + 1], vz = vec[3 * e + 2];

    float inv_d = 1.0f / d;
    float x = fminf(fmaxf(d * 0.5f, 0.0f), 1.0f);
    float x2 = x * x, x3 = x2 * x;
    float sw = 1.0f - x3 * (10.0f - 15.0f * x + 6.0f * x2);
    float chi = sw / sqrtf(d * d + 1.0f) + (1.0f - sw) * inv_d;
    float chi2 = chi * chi, chi3 = chi2 * chi;

    float qu = q[u], qv = q[v];
    const float* mu_u = mu + 3 * u;
    const float* mu_v = mu + 3 * v;
    float dot_uv = (vx * mu_v[0] + vy * mu_v[1] + vz * mu_v[2]) * inv_d;
    float dot_vu = (vx * mu_u[0] + vy * mu_u[1] + vz * mu_u[2]) * inv_d;
    float mudot  = mu_u[0] * mu_v[0] + mu_u[1] * mu_v[1] + mu_u[2] * mu_v[2];

    float Eelec = qu * qv * chi
                + 2.0f * qu * dot_uv * chi2
                + (mudot - 3.0f * dot_uv * dot_vu) * chi3;

    const float* Qv = quad + 9 * v;
    float s = vx * (vx * Qv[0] + vy * Qv[1] + vz * Qv[2])
            + vy * (vx * Qv[3] + vy * Qv[4] + vz * Qv[5])
            + vz * (vx * Qv[6] + vy * Qv[7] + vz * Qv[8]);
    float tr = Qv[0] + Qv[4] + Qv[8];
    float n2 = vx * vx + vy * vy + vz * vz;
    float sum_uv = (s - n2 * (1.0f / 3.0f) * tr) * (inv_d * inv_d);

    Eelec += qu * sum_uv * chi3;
    out[e] = (d <= CUTOFF) ? (KEHALF * Eelec) : 0.0f;
}

extern "C" void kernel_launch(void* const* d_in, const int* in_sizes, int n_in,
                              void* d_out, int out_size, void* d_ws, size_t ws_size,
                              hipStream_t stream) {
    const float* dist  = (const float*)d_in[0];
    const float* vec   = (const float*)d_in[1];
    const float* q     = (const float*)d_in[2];
    const float* mu    = (const float*)d_in[3];
    const float* quad  = (const float*)d_in[4];
    const int*   idx_u = (const int*)d_in[5];
    const int*   idx_v = (const int*)d_in[6];
    float* out = (float*)d_out;

    int E = in_sizes[0];
    int N = in_sizes[2];  // atomic_charges count == N_ATOMS

    size_t need = (size_t)N * 16;  // 16 B per atom
    if (ws_size >= need) {
        unsigned int* T = (unsigned int*)d_ws;
        pack_atoms16<<<(N + 255) / 256, 256, 0, stream>>>(q, mu, quad, T, N);
        int threads = (E + 1) / 2;
        damped_elec_p16e2<<<(threads + 255) / 256, 256, 0, stream>>>(
            dist, vec, T, idx_u, idx_v, out, E);
    } else {
        damped_elec_direct<<<(E + 255) / 256, 256, 0, stream>>>(
            dist, vec, q, mu, quad, idx_u, idx_v, out, E);
    }
}

// Round 13
// 141.518 us; speedup vs baseline: 1.0356x; 1.0356x over previous
//
#include <hip/hip_runtime.h>

#define KEHALF 7.199822675975274f
#define CUTOFF 12.0f

typedef float    fx4 __attribute__((ext_vector_type(4)));
typedef int      ix4 __attribute__((ext_vector_type(4)));
typedef int      ix2 __attribute__((ext_vector_type(2)));
typedef _Float16 hx4 __attribute__((ext_vector_type(4)));

static __device__ __forceinline__ hx4 as_h4(ix2 v) { union { ix2 i; hx4 h; } u; u.i = v; return u.h; }
static __device__ __forceinline__ float h2f_bits(unsigned int hb) {
    union { unsigned short u; _Float16 h; } c; c.u = (unsigned short)hb; return (float)c.h;
}
static __device__ __forceinline__ unsigned int f2h_bits(float f) {
    union { _Float16 h; unsigned short u; } c; c.h = (_Float16)f; return (unsigned int)c.u;
}

// ---- Pack kernel: T[atom] = 16 B: d0,d1 = {q,mu} fp16; d2,d3 = 5 quad vals
// (traceless-symmetric reduced) at 13/12-bit rounded fp16. Table 1.6 MB ->
// fully L2-resident per XCD.
// Tuning ledger (MI355X, 3.2M edges):
//  - gathers MUST be normal-cached: nt gathers defeat L2 retention (44->134MB fetch, 2x time)
//  - EPT sweep 2/4/8 = 47/43/52us: 4 edges/thread is the optimum
//  - single keep-live window beats compiler-sunk gathers (62->45us) and
//    beats explicit cross-batch pipelining (65us regression)
__global__ __launch_bounds__(256)
void pack_atoms16(const float* __restrict__ q,
                  const float* __restrict__ mu,
                  const float* __restrict__ quad,
                  unsigned int* __restrict__ T, int N) {
    int a = blockIdx.x * blockDim.x + threadIdx.x;
    if (a >= N) return;
    const float* m = mu + 3 * a;
    const float* Q = quad + 9 * a;
    float Q00 = Q[0], Q01 = Q[1], Q02 = Q[2];
    float Q10 = Q[3], Q11 = Q[4], Q12 = Q[5];
    float Q20 = Q[6], Q21 = Q[7], Q22 = Q[8];
    float tr3 = (Q00 + Q11 + Q22) * (1.0f / 3.0f);
    unsigned int t00 = ((f2h_bits(Q00 - tr3) + 4u) >> 3) & 0x1FFFu;
    unsigned int t11 = ((f2h_bits(Q11 - tr3) + 4u) >> 3) & 0x1FFFu;
    unsigned int t01 = ((f2h_bits(Q01 + Q10) + 4u) >> 3) & 0x1FFFu;
    unsigned int t02 = ((f2h_bits(Q02 + Q20) + 4u) >> 3) & 0x1FFFu;
    unsigned int t12 = ((f2h_bits(Q12 + Q21) + 8u) >> 4) & 0xFFFu;  // 12-bit
    unsigned int d0 = f2h_bits(q[a]) | (f2h_bits(m[0]) << 16);
    unsigned int d1 = f2h_bits(m[1]) | (f2h_bits(m[2]) << 16);
    unsigned int d2 = t00 | (t11 << 13) | ((t12 & 0x3Fu) << 26);
    unsigned int d3 = t01 | (t02 << 13) | ((t12 >> 6) << 26);
    ix4 e = {(int)d0, (int)d1, (int)d2, (int)d3};
    *reinterpret_cast<ix4*>(T + 4 * (long)a) = e;
}

// ---- Per-edge physics (decodes packed v-entry) ----
static __device__ __forceinline__ float edgeE(float d, float vx, float vy, float vz,
                                              hx4 au, ix4 gv) {
    float inv_d = __builtin_amdgcn_rcpf(d);
    float x = fminf(fmaxf(d * 0.5f, 0.0f), 1.0f);
    float x2 = x * x, x3 = x2 * x;
    float sw = 1.0f - x3 * (10.0f - 15.0f * x + 6.0f * x2);
    float chi = sw * __builtin_amdgcn_rsqf(d * d + 1.0f) + (1.0f - sw) * inv_d;
    float chi2 = chi * chi, chi3 = chi2 * chi;

    float qu    = (float)au[0];
    float mux_u = (float)au[1], muy_u = (float)au[2], muz_u = (float)au[3];

    ix2 vlo = {gv.x, gv.y};
    hx4 av = as_h4(vlo);
    float qv    = (float)av[0];
    float mux_v = (float)av[1], muy_v = (float)av[2], muz_v = (float)av[3];

    unsigned int d2b = (unsigned int)gv.z, d3b = (unsigned int)gv.w;
    float p00 = h2f_bits((d2b & 0x1FFFu) << 3);
    float p11 = h2f_bits(((d2b >> 13) & 0x1FFFu) << 3);
    float s01 = h2f_bits((d3b & 0x1FFFu) << 3);
    float s02 = h2f_bits(((d3b >> 13) & 0x1FFFu) << 3);
    float s12 = h2f_bits((((d3b >> 26) << 6) | (d2b >> 26)) << 4);
    float p22 = -(p00 + p11);  // traceless: exact reconstruction

    float dot_uv = (vx * mux_v + vy * muy_v + vz * muz_v) * inv_d;
    float dot_vu = (vx * mux_u + vy * muy_u + vz * muz_u) * inv_d;
    float mudot  = mux_u * mux_v + muy_u * muy_v + muz_u * muz_v;

    float E = qu * qv * chi
            + 2.0f * qu * dot_uv * chi2
            + (mudot - 3.0f * dot_uv * dot_vu) * chi3;

    float s = vx * (vx * p00 + vy * s01 + vz * s02)
            + vy * (vy * p11 + vz * s12)
            + vz * (vz * p22);
    E += qu * (s * inv_d * inv_d) * chi3;
    return (d <= CUTOFF) ? (KEHALF * E) : 0.0f;
}

// ---- Main kernel: 4 edges/thread, single latency window, L2-cached gathers ----
__global__ __launch_bounds__(256)
void damped_elec_p16(const float* __restrict__ dist,
                     const float* __restrict__ vec,
                     const unsigned int* __restrict__ T,
                     const int* __restrict__ iu,
                     const int* __restrict__ iv,
                     float* __restrict__ out, int E) {
    int t = blockIdx.x * blockDim.x + threadIdx.x;
    int e0 = t * 4;
    if (e0 >= E) return;

    if (e0 + 4 <= E) {
        // Index loads first (head of critical chain) — normal caching.
        ix4 u4 = *reinterpret_cast<const ix4*>(iu + e0);
        ix4 v4 = *reinterpret_cast<const ix4*>(iv + e0);
        // Pure streaming data: non-temporal (keep L2 for the atom table).
        fx4 d4 = __builtin_nontemporal_load(reinterpret_cast<const fx4*>(dist + e0));
        fx4 va = __builtin_nontemporal_load(reinterpret_cast<const fx4*>(vec + 3 * e0));
        fx4 vb = __builtin_nontemporal_load(reinterpret_cast<const fx4*>(vec + 3 * e0 + 4));
        fx4 vc = __builtin_nontemporal_load(reinterpret_cast<const fx4*>(vec + 3 * e0 + 8));

        int ub[4]  = {u4.x, u4.y, u4.z, u4.w};
        int vbi[4] = {v4.x, v4.y, v4.z, v4.w};

        // Gather phase: 2 loads per edge (u: 8 B, v: 16 B), NORMAL caching
        // (L2-resident table), all issued back-to-back.
        ix2 gu[4];
        ix4 gv[4];
#pragma unroll
        for (int k = 0; k < 4; ++k) {
            const unsigned int* pu = T + ((long)ub[k] << 2);
            const unsigned int* pv = T + ((long)vbi[k] << 2);
            gu[k] = *reinterpret_cast<const ix2*>(pu);
            gv[k] = *reinterpret_cast<const ix4*>(pv);
        }

        // Keep-live fence: one latency window, no sinking into compute.
        asm volatile("" : "+v"(d4), "+v"(va), "+v"(vb), "+v"(vc),
                          "+v"(gu[0]), "+v"(gu[1]), "+v"(gu[2]), "+v"(gu[3]),
                          "+v"(gv[0]), "+v"(gv[1]), "+v"(gv[2]), "+v"(gv[3]) :: "memory");

        float db[4]   = {d4.x, d4.y, d4.z, d4.w};
        float vvv[12] = {va.x, va.y, va.z, va.w,
                         vb.x, vb.y, vb.z, vb.w,
                         vc.x, vc.y, vc.z, vc.w};

        float res[4];
#pragma unroll
        for (int k = 0; k < 4; ++k) {
            res[k] = edgeE(db[k], vvv[3 * k + 0], vvv[3 * k + 1], vvv[3 * k + 2],
                           as_h4(gu[k]), gv[k]);
        }
        fx4 o4 = {res[0], res[1], res[2], res[3]};
        __builtin_nontemporal_store(o4, reinterpret_cast<fx4*>(out + e0));
    } else {
        // Scalar tail (E % 4 != 0 only).
        for (int e = e0; e < E; ++e) {
            int u = iu[e], v = iv[e];
            ix2 gu = *reinterpret_cast<const ix2*>(T + ((long)u << 2));
            ix4 gv = *reinterpret_cast<const ix4*>(T + ((long)v << 2));
            out[e] = edgeE(dist[e], vec[3 * e + 0], vec[3 * e + 1], vec[3 * e + 2],
                           as_h4(gu), gv);
        }
    }
}

// ---- Fallback (ws too small): direct scalar-gather kernel ----
__global__ __launch_bounds__(256)
void damped_elec_direct(const float* __restrict__ dist,
                        const float* __restrict__ vec,
                        const float* __restrict__ q,
                        const float* __restrict__ mu,
                        const float* __restrict__ quad,
                        const int* __restrict__ idx_u,
                        const int* __restrict__ idx_v,
                        float* __restrict__ out, int E) {
    int e = blockIdx.x * blockDim.x + threadIdx.x;
    if (e >= E) return;
    float d = dist[e];
    int u = idx_u[e], v = idx_v[e];
    float vx = vec[3 * e + 0], vy = vec[3 * e + 1], vz = vec[3 * e + 2];

    float inv_d = 1.0f / d;
    float x = fminf(fmaxf(d * 0.5f, 0.0f), 1.0f);
    float x2 = x * x, x3 = x2 * x;
    float sw = 1.0f - x3 * (10.0f - 15.0f * x + 6.0f * x2);
    float chi = sw / sqrtf(d * d + 1.0f) + (1.0f - sw) * inv_d;
    float chi2 = chi * chi, chi3 = chi2 * chi;

    float qu = q[u], qv = q[v];
    const float* mu_u = mu + 3 * u;
    const float* mu_v = mu + 3 * v;
    float dot_uv = (vx * mu_v[0] + vy * mu_v[1] + vz * mu_v[2]) * inv_d;
    float dot_vu = (vx * mu_u[0] + vy * mu_u[1] + vz * mu_u[2]) * inv_d;
    float mudot  = mu_u[0] * mu_v[0] + mu_u[1] * mu_v[1] + mu_u[2] * mu_v[2];

    float Eelec = qu * qv * chi
                + 2.0f * qu * dot_uv * chi2
                + (mudot - 3.0f * dot_uv * dot_vu) * chi3;

    const float* Qv = quad + 9 * v;
    float s = vx * (vx * Qv[0] + vy * Qv[1] + vz * Qv[2])
            + vy * (vx * Qv[3] + vy * Qv[4] + vz * Qv[5])
            + vz * (vx * Qv[6] + vy * Qv[7] + vz * Qv[8]);
    float tr = Qv[0] + Qv[4] + Qv[8];
    float n2 = vx * vx + vy * vy + vz * vz;
    float sum_uv = (s - n2 * (1.0f / 3.0f) * tr) * (inv_d * inv_d);

    Eelec += qu * sum_uv * chi3;
    out[e] = (d <= CUTOFF) ? (KEHALF * Eelec) : 0.0f;
}

extern "C" void kernel_launch(void* const* d_in, const int* in_sizes, int n_in,
                              void* d_out, int out_size, void* d_ws, size_t ws_size,
                              hipStream_t stream) {
    const float* dist  = (const float*)d_in[0];
    const float* vec   = (const float*)d_in[1];
    const float* q     = (const float*)d_in[2];
    const float* mu    = (const float*)d_in[3];
    const float* quad  = (const float*)d_in[4];
    const int*   idx_u = (const int*)d_in[5];
    const int*   idx_v = (const int*)d_in[6];
    float* out = (float*)d_out;

    int E = in_sizes[0];
    int N = in_sizes[2];  // atomic_charges count == N_ATOMS

    size_t need = (size_t)N * 16;  // 16 B per atom
    if (ws_size >= need) {
        unsigned int* T = (unsigned int*)d_ws;
        pack_atoms16<<<(N + 255) / 256, 256, 0, stream>>>(q, mu, quad, T, N);
        int threads = (E + 3) / 4;
        damped_elec_p16<<<(threads + 255) / 256, 256, 0, stream>>>(
            dist, vec, T, idx_u, idx_v, out, E);
    } else {
        damped_elec_direct<<<(E + 255) / 256, 256, 0, stream>>>(
            dist, vec, q, mu, quad, idx_u, idx_v, out, E);
    }
}